// Round 5
// baseline (93.844 us; speedup 1.0000x reference)
//
#include <hip/hip_runtime.h>

// LabelSmoothing: weighted soft-target CE, C=3, prefix-valid mask, per-sample
// mean, batch sum. Contiguous-prefix structure per chunk:
//   first row zero   -> empty chunk     -> no bulk loads
//   last row nonzero -> full chunk      -> 12 hoisted unconditional loads
//   else             -> boundary chunk  -> 12-probe binary search for prefix
//                       end, then unconditional loads over the valid region
// Round-5: single fused kernel. Decoupled last-block completion (threadfence +
// device-scope atomic counter, counter zeroed by 4-byte hipMemsetAsync) does
// the per-sample mean + batch sum in the last block -> no ls_final dispatch.

#define NB      512
#define NS      16384
#define NSPLIT  4
#define RPB     (NS / NSPLIT)   // 4096 rows per chunk
#define NTH     512
#define GRP     (RPB / 4)       // 1024 four-row groups per chunk
#define NBLK    (NB * NSPLIT)   // 2048 blocks

// ws layout
#define PSUM_OFF 0
#define PCNT_OFF (NBLK * 4)
#define CNTR_OFF (NBLK * 8)

__device__ __forceinline__ float row_loss(float xa, float xb, float xc,
                                          int la, int lb, int lc) {
    const float w0 = 1.23954983922f, w1 = 5.3172413793f, w2 = 192.75f;
    float m   = fmaxf(fmaxf(xa, xb), xc);
    float lse = m + __logf(__expf(xa - m) + __expf(xb - m) + __expf(xc - m));
    return w0 * (float)la * (lse - xa)
         + w1 * (float)lb * (lse - xb)
         + w2 * (float)lc * (lse - xc);
}

__global__ __launch_bounds__(NTH) void ls_fused(
    const float* __restrict__ x, const int* __restrict__ lab,
    float* __restrict__ psum, int* __restrict__ pcnt,
    unsigned int* __restrict__ barrier_cnt, float* __restrict__ out)
{
    const int blk = blockIdx.x;           // 0 .. NBLK-1
    const int b   = blk & (NB - 1);       // sp-major: consecutive blocks ->
    const int sp  = blk >> 9;             // consecutive samples, same split
    const long long base = ((long long)b * NS + (long long)sp * RPB) * 3;
    const int*   lr = lab + base;
    const float* xr = x   + base;

    __shared__ float ssum[NTH / 64];
    __shared__ unsigned int s_last;

    // chunk classification (uniform across block), independent loads
    int f0 = lr[0], f1 = lr[1], f2 = lr[2];
    int e0 = lr[(RPB - 1) * 3], e1 = lr[(RPB - 1) * 3 + 1], e2 = lr[(RPB - 1) * 3 + 2];

    float tot = 0.0f;                     // block total (valid in thread 0)
    int   bc  = 0;                        // block valid-row count (uniform)

    if ((f0 | f1 | f2) != 0) {
        float sumA = 0.0f, sumB = 0.0f;

        if ((e0 | e1 | e2) != 0) {
            // ---- full chunk: hoist ALL loads, 12 x 16B in flight ----
            const int g0 = threadIdx.x;
            const int g1 = threadIdx.x + NTH;
            const int4*   lp0 = (const int4*)lr + (size_t)g0 * 3;
            const int4*   lp1 = (const int4*)lr + (size_t)g1 * 3;
            const float4* xp0 = (const float4*)xr + (size_t)g0 * 3;
            const float4* xp1 = (const float4*)xr + (size_t)g1 * 3;

            int4   a0 = lp0[0], a1 = lp0[1], a2 = lp0[2];
            int4   b0 = lp1[0], b1 = lp1[1], b2 = lp1[2];
            float4 u0 = xp0[0], u1 = xp0[1], u2 = xp0[2];
            float4 v0 = xp1[0], v1 = xp1[1], v2 = xp1[2];

            sumA += row_loss(u0.x, u0.y, u0.z, a0.x, a0.y, a0.z);
            sumB += row_loss(u0.w, u1.x, u1.y, a0.w, a1.x, a1.y);
            sumA += row_loss(u1.z, u1.w, u2.x, a1.z, a1.w, a2.x);
            sumB += row_loss(u2.y, u2.z, u2.w, a2.y, a2.z, a2.w);
            sumA += row_loss(v0.x, v0.y, v0.z, b0.x, b0.y, b0.z);
            sumB += row_loss(v0.w, v1.x, v1.y, b0.w, b1.x, b1.y);
            sumA += row_loss(v1.z, v1.w, v2.x, b1.z, b1.w, b2.x);
            sumB += row_loss(v2.y, v2.z, v2.w, b2.y, b2.z, b2.w);
            bc = RPB;
        } else {
            // ---- boundary chunk: binary search prefix end (uniform) ----
            int lo = 0, hi = RPB - 1;     // lo valid, hi invalid
            while (hi - lo > 1) {
                int mid = (lo + hi) >> 1;
                const int* p = lr + (size_t)mid * 3;
                if ((p[0] | p[1] | p[2]) != 0) lo = mid; else hi = mid;
            }
            const int nv  = hi;           // rows [0, nv) valid, 1 <= nv < RPB
            const int ngf = nv >> 2;      // full 4-row groups

            for (int g = threadIdx.x; g < ngf; g += NTH) {
                const int4*   lp = (const int4*)lr + (size_t)g * 3;
                const float4* xp = (const float4*)xr + (size_t)g * 3;
                int4   l0 = lp[0], l1 = lp[1], l2 = lp[2];
                float4 x0 = xp[0], x1 = xp[1], x2 = xp[2];
                sumA += row_loss(x0.x, x0.y, x0.z, l0.x, l0.y, l0.z);
                sumB += row_loss(x0.w, x1.x, x1.y, l0.w, l1.x, l1.y);
                sumA += row_loss(x1.z, x1.w, x2.x, l1.z, l1.w, l2.x);
                sumB += row_loss(x2.y, x2.z, x2.w, l2.y, l2.z, l2.w);
            }
            const int rem = nv & 3;
            if (threadIdx.x == 0 && rem) {
                const int r0 = ngf << 2;
                for (int r = 0; r < rem; ++r) {
                    const int*   lp = lr + (size_t)(r0 + r) * 3;
                    const float* xp = xr + (size_t)(r0 + r) * 3;
                    sumA += row_loss(xp[0], xp[1], xp[2], lp[0], lp[1], lp[2]);
                }
            }
            bc = nv;
        }

        // wave (64-lane) + block reduction of the loss sum
        float sum = sumA + sumB;
#pragma unroll
        for (int off = 32; off > 0; off >>= 1) sum += __shfl_down(sum, off);
        const int lane = threadIdx.x & 63;
        const int wid  = threadIdx.x >> 6;
        if (lane == 0) ssum[wid] = sum;
        __syncthreads();
        if (threadIdx.x == 0) {
#pragma unroll
            for (int i = 0; i < NTH / 64; ++i) tot += ssum[i];
        }
        __syncthreads();                  // ssum reused by finisher below
    }

    // ---- epilogue: publish partials; last block reduces ----
    if (threadIdx.x == 0) {
        psum[blk] = tot;
        pcnt[blk] = bc;
        __threadfence();                  // device-scope release of partials
        unsigned int t = atomicAdd(barrier_cnt, 1u);
        s_last = (t == (unsigned int)(NBLK - 1)) ? 1u : 0u;
    }
    __syncthreads();

    if (s_last) {
        __threadfence();                  // acquire: see all blocks' partials
        const int t = threadIdx.x;        // one thread per sample
        float s = 0.0f; int c = 0;
#pragma unroll
        for (int i = 0; i < NSPLIT; ++i) {
            s += psum[i * NB + t];
            c += pcnt[i * NB + t];
        }
        float per = s / (float)c;         // c >= 1 (lengths are 1..S)

#pragma unroll
        for (int off = 32; off > 0; off >>= 1) per += __shfl_down(per, off);
        const int lane = threadIdx.x & 63;
        const int wid  = threadIdx.x >> 6;
        if (lane == 0) ssum[wid] = per;
        __syncthreads();
        if (threadIdx.x == 0) {
            float o = 0.0f;
#pragma unroll
            for (int i = 0; i < NTH / 64; ++i) o += ssum[i];
            out[0] = o;
        }
    }
}

extern "C" void kernel_launch(void* const* d_in, const int* in_sizes, int n_in,
                              void* d_out, int out_size, void* d_ws, size_t ws_size,
                              hipStream_t stream)
{
    const float* x   = (const float*)d_in[0];
    const int*   lab = (const int*)d_in[1];

    float*        psum = (float*)((char*)d_ws + PSUM_OFF);
    int*          pcnt = (int*)((char*)d_ws + PCNT_OFF);
    unsigned int* cntr = (unsigned int*)((char*)d_ws + CNTR_OFF);

    hipMemsetAsync(cntr, 0, sizeof(unsigned int), stream);
    ls_fused<<<NBLK, NTH, 0, stream>>>(x, lab, psum, pcnt, cntr, (float*)d_out);
}

// Round 6
// 26.906 us; speedup vs baseline: 3.4878x; 3.4878x over previous
//
#include <hip/hip_runtime.h>

// LabelSmoothing: weighted soft-target CE, C=3, prefix-valid mask, per-sample
// mean, batch sum. Two-kernel structure (round-5 fused epilogue regressed 3.6x:
// device-scope fence = L2 writeback + serialized single-address atomics).
// Per chunk (contiguous prefix):
//   first row zero   -> empty chunk    -> no bulk loads
//   last row nonzero -> full chunk     -> 12 hoisted unconditional 16B loads
//   else             -> boundary chunk -> 2-phase PARALLEL probe (ballot+
//                       popcount over monotone prefix) finds nv in ~2 round
//                       trips, then unconditional loads over valid region only

#define NB      512
#define NS      16384
#define NSPLIT  4
#define RPB     (NS / NSPLIT)   // 4096 rows per chunk
#define NTH     512
#define NBLK    (NB * NSPLIT)   // 2048 blocks
#define PSTRIDE (RPB / NTH)     // 8: probe stride for boundary phase 1

__device__ __forceinline__ float row_loss(float xa, float xb, float xc,
                                          int la, int lb, int lc) {
    const float w0 = 1.23954983922f, w1 = 5.3172413793f, w2 = 192.75f;
    float m   = fmaxf(fmaxf(xa, xb), xc);
    float lse = m + __logf(__expf(xa - m) + __expf(xb - m) + __expf(xc - m));
    return w0 * (float)la * (lse - xa)
         + w1 * (float)lb * (lse - xb)
         + w2 * (float)lc * (lse - xc);
}

__global__ __launch_bounds__(NTH) void ls_partial(
    const float* __restrict__ x, const int* __restrict__ lab,
    float* __restrict__ psum, int* __restrict__ pcnt)
{
    const int blk = blockIdx.x;           // 0 .. NBLK-1
    const int b   = blk & (NB - 1);       // sp-major: consecutive blocks ->
    const int sp  = blk >> 9;             // consecutive samples, same split
    const long long base = ((long long)b * NS + (long long)sp * RPB) * 3;
    const int*   lr = lab + base;
    const float* xr = x   + base;

    const int lane = threadIdx.x & 63;
    const int wid  = threadIdx.x >> 6;
    __shared__ float ssum[NTH / 64];
    __shared__ int   sint[NTH / 64];
    __shared__ int   s_nv;

    // chunk classification (uniform across block), independent loads
    int f0 = lr[0], f1 = lr[1], f2 = lr[2];
    int e0 = lr[(RPB - 1) * 3], e1 = lr[(RPB - 1) * 3 + 1], e2 = lr[(RPB - 1) * 3 + 2];

    if ((f0 | f1 | f2) == 0) {            // whole chunk past the prefix
        if (threadIdx.x == 0) { psum[blk] = 0.0f; pcnt[blk] = 0; }
        return;
    }

    float sumA = 0.0f, sumB = 0.0f;
    int   cnt = 0;

    if ((e0 | e1 | e2) != 0) {
        // ---- full chunk: hoist ALL loads, 12 x 16B in flight ----
        const int g0 = threadIdx.x;
        const int g1 = threadIdx.x + NTH;
        const int4*   lp0 = (const int4*)lr + (size_t)g0 * 3;
        const int4*   lp1 = (const int4*)lr + (size_t)g1 * 3;
        const float4* xp0 = (const float4*)xr + (size_t)g0 * 3;
        const float4* xp1 = (const float4*)xr + (size_t)g1 * 3;

        int4   a0 = lp0[0], a1 = lp0[1], a2 = lp0[2];
        int4   b0 = lp1[0], b1 = lp1[1], b2 = lp1[2];
        float4 u0 = xp0[0], u1 = xp0[1], u2 = xp0[2];
        float4 v0 = xp1[0], v1 = xp1[1], v2 = xp1[2];

        sumA += row_loss(u0.x, u0.y, u0.z, a0.x, a0.y, a0.z);
        sumB += row_loss(u0.w, u1.x, u1.y, a0.w, a1.x, a1.y);
        sumA += row_loss(u1.z, u1.w, u2.x, a1.z, a1.w, a2.x);
        sumB += row_loss(u2.y, u2.z, u2.w, a2.y, a2.z, a2.w);
        sumA += row_loss(v0.x, v0.y, v0.z, b0.x, b0.y, b0.z);
        sumB += row_loss(v0.w, v1.x, v1.y, b0.w, b1.x, b1.y);
        sumA += row_loss(v1.z, v1.w, v2.x, b1.z, b1.w, b2.x);
        sumB += row_loss(v2.y, v2.z, v2.w, b2.y, b2.z, b2.w);
        cnt = RPB;
    } else {
        // ---- boundary chunk: 2-phase parallel probe for prefix end ----
        // phase 1: 512 parallel probes at stride 8; prefix monotone =>
        // #nonzero = ceil(nv/8)
        {
            const int* p1 = lr + (size_t)threadIdx.x * PSTRIDE * 3;
            int nz1 = p1[0] | p1[1] | p1[2];
            unsigned long long m1 = __ballot(nz1 != 0);
            if (lane == 0) sint[wid] = __popcll(m1);
        }
        __syncthreads();
        int count1 = 0;
#pragma unroll
        for (int i = 0; i < NTH / 64; ++i) count1 += sint[i];
        const int base_row = (count1 - 1) * PSTRIDE;   // valid; nv in (base, base+8]

        // phase 2: 8 parallel probes of the bucket
        {
            int nz2 = 0;
            if (threadIdx.x < PSTRIDE) {
                const int* p2 = lr + (size_t)(base_row + threadIdx.x) * 3;
                nz2 = ((p2[0] | p2[1] | p2[2]) != 0) ? 1 : 0;
            }
            unsigned long long m2 = __ballot(nz2 != 0);
            if (threadIdx.x == 0) s_nv = base_row + __popcll(m2);
        }
        __syncthreads();
        const int nv  = s_nv;             // rows [0, nv) valid, 1 <= nv < RPB
        const int ngf = nv >> 2;          // full 4-row groups

        // bulk: unconditional hoisted loads over the valid region only
        for (int g = threadIdx.x; g < ngf; g += NTH) {
            const int4*   lp = (const int4*)lr + (size_t)g * 3;
            const float4* xp = (const float4*)xr + (size_t)g * 3;
            int4   l0 = lp[0], l1 = lp[1], l2 = lp[2];
            float4 x0 = xp[0], x1 = xp[1], x2 = xp[2];
            sumA += row_loss(x0.x, x0.y, x0.z, l0.x, l0.y, l0.z);
            sumB += row_loss(x0.w, x1.x, x1.y, l0.w, l1.x, l1.y);
            sumA += row_loss(x1.z, x1.w, x2.x, l1.z, l1.w, l2.x);
            sumB += row_loss(x2.y, x2.z, x2.w, l2.y, l2.z, l2.w);
        }
        const int rem = nv & 3;
        if (threadIdx.x == 0 && rem) {
            const int r0 = ngf << 2;
            for (int r = 0; r < rem; ++r) {
                const int*   lp = lr + (size_t)(r0 + r) * 3;
                const float* xp = xr + (size_t)(r0 + r) * 3;
                sumA += row_loss(xp[0], xp[1], xp[2], lp[0], lp[1], lp[2]);
            }
        }
        cnt = nv;
        __syncthreads();                  // sint reuse below
    }

    // wave (64-lane) + block reduction
    float sum = sumA + sumB;
#pragma unroll
    for (int off = 32; off > 0; off >>= 1) sum += __shfl_down(sum, off);
    if (lane == 0) ssum[wid] = sum;
    __syncthreads();
    if (threadIdx.x == 0) {
        float ts = 0.0f;
#pragma unroll
        for (int i = 0; i < NTH / 64; ++i) ts += ssum[i];
        psum[blk] = ts;
        pcnt[blk] = cnt;                  // uniform per block
    }
}

__global__ __launch_bounds__(NB) void ls_final(
    const float* __restrict__ psum, const int* __restrict__ pcnt,
    float* __restrict__ out)
{
    const int b = threadIdx.x;            // one thread per sample
    float s = 0.0f; int c = 0;
#pragma unroll
    for (int i = 0; i < NSPLIT; ++i) {
        s += psum[i * NB + b];            // sp-major layout
        c += pcnt[i * NB + b];
    }
    float per = s / (float)c;             // c >= 1 (lengths are 1..S)

#pragma unroll
    for (int off = 32; off > 0; off >>= 1) per += __shfl_down(per, off);
    __shared__ float sh[NB / 64];
    const int lane = threadIdx.x & 63;
    const int wid  = threadIdx.x >> 6;
    if (lane == 0) sh[wid] = per;
    __syncthreads();
    if (threadIdx.x == 0) {
        float t = 0.0f;
#pragma unroll
        for (int i = 0; i < NB / 64; ++i) t += sh[i];
        out[0] = t;
    }
}

extern "C" void kernel_launch(void* const* d_in, const int* in_sizes, int n_in,
                              void* d_out, int out_size, void* d_ws, size_t ws_size,
                              hipStream_t stream)
{
    const float* x   = (const float*)d_in[0];
    const int*   lab = (const int*)d_in[1];

    float* psum = (float*)d_ws;
    int*   pcnt = (int*)((char*)d_ws + (size_t)NBLK * sizeof(float));

    ls_partial<<<NBLK, NTH, 0, stream>>>(x, lab, psum, pcnt);
    ls_final<<<1, NB, 0, stream>>>(psum, pcnt, (float*)d_out);
}

// Round 7
// 25.066 us; speedup vs baseline: 3.7439x; 1.0734x over previous
//
#include <hip/hip_runtime.h>

// LabelSmoothing: weighted soft-target CE, C=3, prefix-valid mask, per-sample
// mean, batch sum. Two-kernel structure. Per chunk (contiguous prefix):
//   first row zero   -> empty chunk    -> no bulk loads
//   last row nonzero -> full chunk     -> 6 hoisted unconditional 16B loads
//   else             -> boundary chunk -> 2-phase parallel probe (ballot+
//                       popcount over monotone prefix), then unconditional
//                       loads over the valid region only
// Round-7: NSPLIT=8 (chunk = 2048 rows = 48 KB): halves the per-block work
// quantum -> 4096 blocks give the scheduler a backfill pool beyond the ~1024
// resident slots, smoothing the end-of-kernel tail that round-4/6 counters
// suggest costs ~15-20%.

#define NB      512
#define NS      16384
#define NSPLIT  8
#define RPB     (NS / NSPLIT)   // 2048 rows per chunk
#define NTH     512
#define NBLK    (NB * NSPLIT)   // 4096 blocks
#define PSTRIDE (RPB / NTH)     // 4: probe stride for boundary phase 1

__device__ __forceinline__ float row_loss(float xa, float xb, float xc,
                                          int la, int lb, int lc) {
    const float w0 = 1.23954983922f, w1 = 5.3172413793f, w2 = 192.75f;
    float m   = fmaxf(fmaxf(xa, xb), xc);
    float lse = m + __logf(__expf(xa - m) + __expf(xb - m) + __expf(xc - m));
    return w0 * (float)la * (lse - xa)
         + w1 * (float)lb * (lse - xb)
         + w2 * (float)lc * (lse - xc);
}

__global__ __launch_bounds__(NTH) void ls_partial(
    const float* __restrict__ x, const int* __restrict__ lab,
    float* __restrict__ psum, int* __restrict__ pcnt)
{
    const int blk = blockIdx.x;           // 0 .. NBLK-1
    const int b   = blk & (NB - 1);       // sp-major: consecutive blocks ->
    const int sp  = blk >> 9;             // consecutive samples, same split
    const long long base = ((long long)b * NS + (long long)sp * RPB) * 3;
    const int*   lr = lab + base;
    const float* xr = x   + base;

    const int lane = threadIdx.x & 63;
    const int wid  = threadIdx.x >> 6;
    __shared__ float ssum[NTH / 64];
    __shared__ int   sint[NTH / 64];
    __shared__ int   s_nv;

    // chunk classification (uniform across block), independent loads
    int f0 = lr[0], f1 = lr[1], f2 = lr[2];
    int e0 = lr[(RPB - 1) * 3], e1 = lr[(RPB - 1) * 3 + 1], e2 = lr[(RPB - 1) * 3 + 2];

    if ((f0 | f1 | f2) == 0) {            // whole chunk past the prefix
        if (threadIdx.x == 0) { psum[blk] = 0.0f; pcnt[blk] = 0; }
        return;
    }

    float sumA = 0.0f, sumB = 0.0f;
    int   cnt = 0;

    if ((e0 | e1 | e2) != 0) {
        // ---- full chunk: one group (4 rows) per thread, 6 x 16B hoisted ----
        const int g0 = threadIdx.x;
        const int4*   lp0 = (const int4*)lr + (size_t)g0 * 3;
        const float4* xp0 = (const float4*)xr + (size_t)g0 * 3;

        int4   a0 = lp0[0], a1 = lp0[1], a2 = lp0[2];
        float4 u0 = xp0[0], u1 = xp0[1], u2 = xp0[2];

        sumA += row_loss(u0.x, u0.y, u0.z, a0.x, a0.y, a0.z);
        sumB += row_loss(u0.w, u1.x, u1.y, a0.w, a1.x, a1.y);
        sumA += row_loss(u1.z, u1.w, u2.x, a1.z, a1.w, a2.x);
        sumB += row_loss(u2.y, u2.z, u2.w, a2.y, a2.z, a2.w);
        cnt = RPB;
    } else {
        // ---- boundary chunk: 2-phase parallel probe for prefix end ----
        // phase 1: 512 probes at stride 4; prefix monotone => count = ceil(nv/4)
        {
            const int* p1 = lr + (size_t)threadIdx.x * PSTRIDE * 3;
            int nz1 = p1[0] | p1[1] | p1[2];
            unsigned long long m1 = __ballot(nz1 != 0);
            if (lane == 0) sint[wid] = __popcll(m1);
        }
        __syncthreads();
        int count1 = 0;
#pragma unroll
        for (int i = 0; i < NTH / 64; ++i) count1 += sint[i];
        const int base_row = (count1 - 1) * PSTRIDE;   // valid; nv in (base, base+4]

        // phase 2: 4 parallel probes of the bucket
        {
            int nz2 = 0;
            if (threadIdx.x < PSTRIDE) {
                const int* p2 = lr + (size_t)(base_row + threadIdx.x) * 3;
                nz2 = ((p2[0] | p2[1] | p2[2]) != 0) ? 1 : 0;
            }
            unsigned long long m2 = __ballot(nz2 != 0);
            if (threadIdx.x == 0) s_nv = base_row + __popcll(m2);
        }
        __syncthreads();
        const int nv  = s_nv;             // rows [0, nv) valid, 1 <= nv < RPB
        const int ngf = nv >> 2;          // full 4-row groups

        // bulk: unconditional hoisted loads over the valid region only
        for (int g = threadIdx.x; g < ngf; g += NTH) {
            const int4*   lp = (const int4*)lr + (size_t)g * 3;
            const float4* xp = (const float4*)xr + (size_t)g * 3;
            int4   l0 = lp[0], l1 = lp[1], l2 = lp[2];
            float4 x0 = xp[0], x1 = xp[1], x2 = xp[2];
            sumA += row_loss(x0.x, x0.y, x0.z, l0.x, l0.y, l0.z);
            sumB += row_loss(x0.w, x1.x, x1.y, l0.w, l1.x, l1.y);
            sumA += row_loss(x1.z, x1.w, x2.x, l1.z, l1.w, l2.x);
            sumB += row_loss(x2.y, x2.z, x2.w, l2.y, l2.z, l2.w);
        }
        const int rem = nv & 3;
        if (threadIdx.x == 0 && rem) {
            const int r0 = ngf << 2;
            for (int r = 0; r < rem; ++r) {
                const int*   lp = lr + (size_t)(r0 + r) * 3;
                const float* xp = xr + (size_t)(r0 + r) * 3;
                sumA += row_loss(xp[0], xp[1], xp[2], lp[0], lp[1], lp[2]);
            }
        }
        cnt = nv;
        __syncthreads();                  // sint reuse below
    }

    // wave (64-lane) + block reduction
    float sum = sumA + sumB;
#pragma unroll
    for (int off = 32; off > 0; off >>= 1) sum += __shfl_down(sum, off);
    if (lane == 0) ssum[wid] = sum;
    __syncthreads();
    if (threadIdx.x == 0) {
        float ts = 0.0f;
#pragma unroll
        for (int i = 0; i < NTH / 64; ++i) ts += ssum[i];
        psum[blk] = ts;
        pcnt[blk] = cnt;                  // uniform per block
    }
}

__global__ __launch_bounds__(NB) void ls_final(
    const float* __restrict__ psum, const int* __restrict__ pcnt,
    float* __restrict__ out)
{
    const int b = threadIdx.x;            // one thread per sample
    float s = 0.0f; int c = 0;
#pragma unroll
    for (int i = 0; i < NSPLIT; ++i) {
        s += psum[i * NB + b];            // sp-major layout
        c += pcnt[i * NB + b];
    }
    float per = s / (float)c;             // c >= 1 (lengths are 1..S)

#pragma unroll
    for (int off = 32; off > 0; off >>= 1) per += __shfl_down(per, off);
    __shared__ float sh[NB / 64];
    const int lane = threadIdx.x & 63;
    const int wid  = threadIdx.x >> 6;
    if (lane == 0) sh[wid] = per;
    __syncthreads();
    if (threadIdx.x == 0) {
        float t = 0.0f;
#pragma unroll
        for (int i = 0; i < NB / 64; ++i) t += sh[i];
        out[0] = t;
    }
}

extern "C" void kernel_launch(void* const* d_in, const int* in_sizes, int n_in,
                              void* d_out, int out_size, void* d_ws, size_t ws_size,
                              hipStream_t stream)
{
    const float* x   = (const float*)d_in[0];
    const int*   lab = (const int*)d_in[1];

    float* psum = (float*)d_ws;
    int*   pcnt = (int*)((char*)d_ws + (size_t)NBLK * sizeof(float));

    ls_partial<<<NBLK, NTH, 0, stream>>>(x, lab, psum, pcnt);
    ls_final<<<1, NB, 0, stream>>>(psum, pcnt, (float*)d_out);
}

// Round 8
// 24.821 us; speedup vs baseline: 3.7808x; 1.0098x over previous
//
#include <hip/hip_runtime.h>

// LabelSmoothing: weighted soft-target CE, C=3, prefix-valid mask, per-sample
// mean, batch sum. Two-kernel structure. Per chunk (contiguous prefix):
//   first row zero   -> empty chunk    -> no bulk loads
//   last row nonzero -> full chunk     -> 6 hoisted unconditional 16B loads
//   else             -> boundary chunk -> 2-phase parallel probe (ballot+
//                       popcount over monotone prefix), then unconditional
//                       loads over the valid region only
// Round-8: NSPLIT=16, NTH=256 (chunk = 1024 rows = 24 KB, 8192 blocks).
// Tail-quantization ladder: 96KB->26.1, 48KB->25.1, now 24KB. Each halving
// of the work quantum halves the last-residency-round imbalance.

#define NB      512
#define NS      16384
#define NSPLIT  16
#define RPB     (NS / NSPLIT)   // 1024 rows per chunk
#define NTH     256
#define NBLK    (NB * NSPLIT)   // 8192 blocks
#define PSTRIDE (RPB / NTH)     // 4: probe stride for boundary phase 1

__device__ __forceinline__ float row_loss(float xa, float xb, float xc,
                                          int la, int lb, int lc) {
    const float w0 = 1.23954983922f, w1 = 5.3172413793f, w2 = 192.75f;
    float m   = fmaxf(fmaxf(xa, xb), xc);
    float lse = m + __logf(__expf(xa - m) + __expf(xb - m) + __expf(xc - m));
    return w0 * (float)la * (lse - xa)
         + w1 * (float)lb * (lse - xb)
         + w2 * (float)lc * (lse - xc);
}

__global__ __launch_bounds__(NTH) void ls_partial(
    const float* __restrict__ x, const int* __restrict__ lab,
    float* __restrict__ psum, int* __restrict__ pcnt)
{
    const int blk = blockIdx.x;           // 0 .. NBLK-1
    const int b   = blk & (NB - 1);       // sp-major: consecutive blocks ->
    const int sp  = blk >> 9;             // consecutive samples, same split
    const long long base = ((long long)b * NS + (long long)sp * RPB) * 3;
    const int*   lr = lab + base;
    const float* xr = x   + base;

    const int lane = threadIdx.x & 63;
    const int wid  = threadIdx.x >> 6;
    __shared__ float ssum[NTH / 64];
    __shared__ int   sint[NTH / 64];
    __shared__ int   s_nv;

    // chunk classification (uniform across block), independent loads
    int f0 = lr[0], f1 = lr[1], f2 = lr[2];
    int e0 = lr[(RPB - 1) * 3], e1 = lr[(RPB - 1) * 3 + 1], e2 = lr[(RPB - 1) * 3 + 2];

    if ((f0 | f1 | f2) == 0) {            // whole chunk past the prefix
        if (threadIdx.x == 0) { psum[blk] = 0.0f; pcnt[blk] = 0; }
        return;
    }

    float sumA = 0.0f, sumB = 0.0f;
    int   cnt = 0;

    if ((e0 | e1 | e2) != 0) {
        // ---- full chunk: one group (4 rows) per thread, 6 x 16B hoisted ----
        const int g0 = threadIdx.x;
        const int4*   lp0 = (const int4*)lr + (size_t)g0 * 3;
        const float4* xp0 = (const float4*)xr + (size_t)g0 * 3;

        int4   a0 = lp0[0], a1 = lp0[1], a2 = lp0[2];
        float4 u0 = xp0[0], u1 = xp0[1], u2 = xp0[2];

        sumA += row_loss(u0.x, u0.y, u0.z, a0.x, a0.y, a0.z);
        sumB += row_loss(u0.w, u1.x, u1.y, a0.w, a1.x, a1.y);
        sumA += row_loss(u1.z, u1.w, u2.x, a1.z, a1.w, a2.x);
        sumB += row_loss(u2.y, u2.z, u2.w, a2.y, a2.z, a2.w);
        cnt = RPB;
    } else {
        // ---- boundary chunk: 2-phase parallel probe for prefix end ----
        // phase 1: 256 probes at stride 4; prefix monotone => count = ceil(nv/4)
        {
            const int* p1 = lr + (size_t)threadIdx.x * PSTRIDE * 3;
            int nz1 = p1[0] | p1[1] | p1[2];
            unsigned long long m1 = __ballot(nz1 != 0);
            if (lane == 0) sint[wid] = __popcll(m1);
        }
        __syncthreads();
        int count1 = 0;
#pragma unroll
        for (int i = 0; i < NTH / 64; ++i) count1 += sint[i];
        const int base_row = (count1 - 1) * PSTRIDE;   // valid; nv in (base, base+4]

        // phase 2: 4 parallel probes of the bucket
        {
            int nz2 = 0;
            if (threadIdx.x < PSTRIDE) {
                const int* p2 = lr + (size_t)(base_row + threadIdx.x) * 3;
                nz2 = ((p2[0] | p2[1] | p2[2]) != 0) ? 1 : 0;
            }
            unsigned long long m2 = __ballot(nz2 != 0);
            if (threadIdx.x == 0) s_nv = base_row + __popcll(m2);
        }
        __syncthreads();
        const int nv  = s_nv;             // rows [0, nv) valid, 1 <= nv < RPB
        const int ngf = nv >> 2;          // full 4-row groups

        // bulk: unconditional hoisted loads over the valid region only
        for (int g = threadIdx.x; g < ngf; g += NTH) {
            const int4*   lp = (const int4*)lr + (size_t)g * 3;
            const float4* xp = (const float4*)xr + (size_t)g * 3;
            int4   l0 = lp[0], l1 = lp[1], l2 = lp[2];
            float4 x0 = xp[0], x1 = xp[1], x2 = xp[2];
            sumA += row_loss(x0.x, x0.y, x0.z, l0.x, l0.y, l0.z);
            sumB += row_loss(x0.w, x1.x, x1.y, l0.w, l1.x, l1.y);
            sumA += row_loss(x1.z, x1.w, x2.x, l1.z, l1.w, l2.x);
            sumB += row_loss(x2.y, x2.z, x2.w, l2.y, l2.z, l2.w);
        }
        const int rem = nv & 3;
        if (threadIdx.x == 0 && rem) {
            const int r0 = ngf << 2;
            for (int r = 0; r < rem; ++r) {
                const int*   lp = lr + (size_t)(r0 + r) * 3;
                const float* xp = xr + (size_t)(r0 + r) * 3;
                sumA += row_loss(xp[0], xp[1], xp[2], lp[0], lp[1], lp[2]);
            }
        }
        cnt = nv;
        __syncthreads();                  // sint reuse below
    }

    // wave (64-lane) + block reduction
    float sum = sumA + sumB;
#pragma unroll
    for (int off = 32; off > 0; off >>= 1) sum += __shfl_down(sum, off);
    if (lane == 0) ssum[wid] = sum;
    __syncthreads();
    if (threadIdx.x == 0) {
        float ts = 0.0f;
#pragma unroll
        for (int i = 0; i < NTH / 64; ++i) ts += ssum[i];
        psum[blk] = ts;
        pcnt[blk] = cnt;                  // uniform per block
    }
}

__global__ __launch_bounds__(NB) void ls_final(
    const float* __restrict__ psum, const int* __restrict__ pcnt,
    float* __restrict__ out)
{
    const int b = threadIdx.x;            // one thread per sample
    float s = 0.0f; int c = 0;
#pragma unroll
    for (int i = 0; i < NSPLIT; ++i) {
        s += psum[i * NB + b];            // sp-major layout
        c += pcnt[i * NB + b];
    }
    float per = s / (float)c;             // c >= 1 (lengths are 1..S)

#pragma unroll
    for (int off = 32; off > 0; off >>= 1) per += __shfl_down(per, off);
    __shared__ float sh[NB / 64];
    const int lane = threadIdx.x & 63;
    const int wid  = threadIdx.x >> 6;
    if (lane == 0) sh[wid] = per;
    __syncthreads();
    if (threadIdx.x == 0) {
        float t = 0.0f;
#pragma unroll
        for (int i = 0; i < NB / 64; ++i) t += sh[i];
        out[0] = t;
    }
}

extern "C" void kernel_launch(void* const* d_in, const int* in_sizes, int n_in,
                              void* d_out, int out_size, void* d_ws, size_t ws_size,
                              hipStream_t stream)
{
    const float* x   = (const float*)d_in[0];
    const int*   lab = (const int*)d_in[1];

    float* psum = (float*)d_ws;
    int*   pcnt = (int*)((char*)d_ws + (size_t)NBLK * sizeof(float));

    ls_partial<<<NBLK, NTH, 0, stream>>>(x, lab, psum, pcnt);
    ls_final<<<1, NB, 0, stream>>>(psum, pcnt, (float*)d_out);
}

// Round 9
// 24.280 us; speedup vs baseline: 3.8650x; 1.0223x over previous
//
#include <hip/hip_runtime.h>

// LabelSmoothing: weighted soft-target CE, C=3, prefix-valid mask, per-sample
// mean, batch sum. Two-kernel structure.
// Round-9 insight: masked compute is FREE -- row_loss of an all-zero label row
// is exactly 0, and cnt derives from the bulk-loaded labels. So per chunk:
//   row 0 zero -> empty chunk -> exit (keeps the ~48 MB empty-region skip)
//   else       -> ONE unconditional bulk round (6x16B hoisted loads/thread),
//                 compute all 4 rows, count nonzero rows, block-reduce.
// This removes the second serial HBM round-trip (full/boundary classification
// + parallel probes) from every nonempty block; boundary blocks read ~24 KB
// past the prefix (+~12 MB total, ~+0.2 us equivalent -- cheap vs the killed
// latency round).

#define NB      512
#define NS      16384
#define NSPLIT  16
#define RPB     (NS / NSPLIT)   // 1024 rows per chunk
#define NTH     256
#define NBLK    (NB * NSPLIT)   // 8192 blocks

__device__ __forceinline__ float row_loss(float xa, float xb, float xc,
                                          int la, int lb, int lc) {
    const float w0 = 1.23954983922f, w1 = 5.3172413793f, w2 = 192.75f;
    float m   = fmaxf(fmaxf(xa, xb), xc);
    float lse = m + __logf(__expf(xa - m) + __expf(xb - m) + __expf(xc - m));
    return w0 * (float)la * (lse - xa)
         + w1 * (float)lb * (lse - xb)
         + w2 * (float)lc * (lse - xc);
}

__global__ __launch_bounds__(NTH) void ls_partial(
    const float* __restrict__ x, const int* __restrict__ lab,
    float* __restrict__ psum, int* __restrict__ pcnt)
{
    const int blk = blockIdx.x;           // 0 .. NBLK-1
    const int b   = blk & (NB - 1);       // sp-major: consecutive blocks ->
    const int sp  = blk >> 9;             // consecutive samples, same split
    const long long base = ((long long)b * NS + (long long)sp * RPB) * 3;
    const int*   lr = lab + base;
    const float* xr = x   + base;

    // single classification probe: row 0 (uniform scalar loads, broadcast)
    int f0 = lr[0], f1 = lr[1], f2 = lr[2];
    if ((f0 | f1 | f2) == 0) {            // whole chunk past the prefix
        if (threadIdx.x == 0) { psum[blk] = 0.0f; pcnt[blk] = 0; }
        return;
    }

    // ---- one unconditional bulk round: 6 x 16B hoisted loads ----
    const int g0 = threadIdx.x;
    const int4*   lp0 = (const int4*)lr + (size_t)g0 * 3;
    const float4* xp0 = (const float4*)xr + (size_t)g0 * 3;

    int4   a0 = lp0[0], a1 = lp0[1], a2 = lp0[2];
    float4 u0 = xp0[0], u1 = xp0[1], u2 = xp0[2];

    // zero-label rows contribute 0 loss and 0 count -- no masking needed
    float sumA = 0.0f, sumB = 0.0f;
    int   cnt  = 0;
    sumA += row_loss(u0.x, u0.y, u0.z, a0.x, a0.y, a0.z);
    cnt  += ((a0.x | a0.y | a0.z) != 0);
    sumB += row_loss(u0.w, u1.x, u1.y, a0.w, a1.x, a1.y);
    cnt  += ((a0.w | a1.x | a1.y) != 0);
    sumA += row_loss(u1.z, u1.w, u2.x, a1.z, a1.w, a2.x);
    cnt  += ((a1.z | a1.w | a2.x) != 0);
    sumB += row_loss(u2.y, u2.z, u2.w, a2.y, a2.z, a2.w);
    cnt  += ((a2.y | a2.z | a2.w) != 0);

    // wave (64-lane) + block reduction of sum and cnt
    float sum = sumA + sumB;
#pragma unroll
    for (int off = 32; off > 0; off >>= 1) {
        sum += __shfl_down(sum, off);
        cnt += __shfl_down(cnt, off);
    }
    __shared__ float ssum[NTH / 64];
    __shared__ int   scnt[NTH / 64];
    const int lane = threadIdx.x & 63;
    const int wid  = threadIdx.x >> 6;
    if (lane == 0) { ssum[wid] = sum; scnt[wid] = cnt; }
    __syncthreads();
    if (threadIdx.x == 0) {
        float ts = 0.0f; int tc = 0;
#pragma unroll
        for (int i = 0; i < NTH / 64; ++i) { ts += ssum[i]; tc += scnt[i]; }
        psum[blk] = ts;
        pcnt[blk] = tc;
    }
}

__global__ __launch_bounds__(NB) void ls_final(
    const float* __restrict__ psum, const int* __restrict__ pcnt,
    float* __restrict__ out)
{
    const int b = threadIdx.x;            // one thread per sample
    float s = 0.0f; int c = 0;
#pragma unroll
    for (int i = 0; i < NSPLIT; ++i) {
        s += psum[i * NB + b];            // sp-major layout
        c += pcnt[i * NB + b];
    }
    float per = s / (float)c;             // c >= 1 (lengths are 1..S)

#pragma unroll
    for (int off = 32; off > 0; off >>= 1) per += __shfl_down(per, off);
    __shared__ float sh[NB / 64];
    const int lane = threadIdx.x & 63;
    const int wid  = threadIdx.x >> 6;
    if (lane == 0) sh[wid] = per;
    __syncthreads();
    if (threadIdx.x == 0) {
        float t = 0.0f;
#pragma unroll
        for (int i = 0; i < NB / 64; ++i) t += sh[i];
        out[0] = t;
    }
}

extern "C" void kernel_launch(void* const* d_in, const int* in_sizes, int n_in,
                              void* d_out, int out_size, void* d_ws, size_t ws_size,
                              hipStream_t stream)
{
    const float* x   = (const float*)d_in[0];
    const int*   lab = (const int*)d_in[1];

    float* psum = (float*)d_ws;
    int*   pcnt = (int*)((char*)d_ws + (size_t)NBLK * sizeof(float));

    ls_partial<<<NBLK, NTH, 0, stream>>>(x, lab, psum, pcnt);
    ls_final<<<1, NB, 0, stream>>>(psum, pcnt, (float*)d_out);
}